// Round 2
// baseline (594.633 us; speedup 1.0000x reference)
//
#include <hip/hip_runtime.h>
#include <stdint.h>

typedef __attribute__((ext_vector_type(8))) short short8;
typedef __attribute__((ext_vector_type(4))) float f32x4;

#define LOG2E 1.4426950408889634f

// workspace layout (bytes)
#define OFF_WT    0u           // W^T bf16 [256][256]            = 131072
#define OFF_WHT   131072u      // Wh^T bf16 [256][8192]          = 4194304
#define OFF_FSRC  4325376u     // f_src f32 [8192]               = 32768
#define OFF_FDST  4358144u     // f_dst f32 [8192]               = 32768
#define OFF_MKEY  4390912u     // max-key u32                    = 64
#define OFF_LP    4390976u     // L partials f32 [4][8192]       = 131072
#define OFF_ACC   4522048u     // ACC partials f32 [4][8192][256]= 33554432
// total = 38,076,480 bytes

__device__ __forceinline__ unsigned short f2bf(float f) {
    union { float f; unsigned int i; } v; v.f = f;
    unsigned int u = v.i;
    return (unsigned short)((u + 0x7FFFu + ((u >> 16) & 1u)) >> 16);
}

// ---------------- K0: W (f32) -> W^T (bf16), init max-key ----------------
__global__ void k0_init(const float* __restrict__ W,
                        unsigned short* __restrict__ WT,
                        unsigned int* __restrict__ Mkey) {
    int idx = blockIdx.x * 256 + threadIdx.x;   // 65536 threads
    int i = idx >> 8, o = idx & 255;
    WT[o * 256 + i] = f2bf(W[i * 256 + o]);
    if (idx == 0) *Mkey = 0u;
}

// ---------------- K1: Wh = X@W (MFMA), write Wh^T bf16, f_src/f_dst, global max f_dst ----------------
__global__ __launch_bounds__(256, 2)
void k1_stage1(const float* __restrict__ X,
               const unsigned short* __restrict__ WT,
               const float* __restrict__ a_src,
               const float* __restrict__ a_dst,
               unsigned short* __restrict__ WhT,
               float* __restrict__ f_src,
               float* __restrict__ f_dst,
               unsigned int* __restrict__ Mkey) {
    const int t = threadIdx.x;
    const int w = t >> 6, lane = t & 63, l15 = lane & 15, q = lane >> 4;
    const int rowbase = blockIdx.x * 64 + w * 16;   // wave owns 16 rows x 256 cols

    f32x4 acc[16];
#pragma unroll
    for (int ct = 0; ct < 16; ++ct) acc[ct] = (f32x4)0.0f;

#pragma unroll
    for (int ks = 0; ks < 8; ++ks) {   // K = 256 in steps of 32
        const float* xrow = X + (size_t)(rowbase + l15) * 256 + ks * 32 + q * 8;
        float4 xa = *(const float4*)(xrow);
        float4 xb = *(const float4*)(xrow + 4);
        short8 a;
        a[0] = (short)f2bf(xa.x); a[1] = (short)f2bf(xa.y);
        a[2] = (short)f2bf(xa.z); a[3] = (short)f2bf(xa.w);
        a[4] = (short)f2bf(xb.x); a[5] = (short)f2bf(xb.y);
        a[6] = (short)f2bf(xb.z); a[7] = (short)f2bf(xb.w);
#pragma unroll
        for (int ct = 0; ct < 16; ++ct) {
            short8 b = *(const short8*)(WT + (size_t)(ct * 16 + l15) * 256 + ks * 32 + q * 8);
            acc[ct] = __builtin_amdgcn_mfma_f32_16x16x32_bf16(a, b, acc[ct], 0, 0, 0);
        }
    }

    // write Wh^T bf16: C/D layout col=lane&15, row=quad*4+reg  [m89/m91]
#pragma unroll
    for (int ct = 0; ct < 16; ++ct) {
        int col = ct * 16 + l15;
        ushort4 v;
        v.x = f2bf(acc[ct][0]); v.y = f2bf(acc[ct][1]);
        v.z = f2bf(acc[ct][2]); v.w = f2bf(acc[ct][3]);
        *(ushort4*)(WhT + (size_t)col * 8192 + rowbase + q * 4) = v;
    }

    // f_src/f_dst: lane-partial over its 16 cols, reduce across the 16 lanes of the quad
    float as[16], ad[16];
#pragma unroll
    for (int ct = 0; ct < 16; ++ct) {
        as[ct] = a_src[ct * 16 + l15];
        ad[ct] = a_dst[ct * 16 + l15];
    }
#pragma unroll
    for (int reg = 0; reg < 4; ++reg) {
        float ps = 0.f, pd = 0.f;
#pragma unroll
        for (int ct = 0; ct < 16; ++ct) {
            ps += acc[ct][reg] * as[ct];
            pd += acc[ct][reg] * ad[ct];
        }
#pragma unroll
        for (int m = 1; m < 16; m <<= 1) {
            ps += __shfl_xor(ps, m, 64);
            pd += __shfl_xor(pd, m, 64);
        }
        if (l15 == 0) {
            int row = rowbase + q * 4 + reg;
            f_src[row] = ps;
            f_dst[row] = pd;
            union { float f; unsigned int u; } cv; cv.f = pd;
            unsigned int key = (cv.u & 0x80000000u) ? ~cv.u : (cv.u | 0x80000000u);
            atomicMax(Mkey, key);
        }
    }
}

// ---------------- K3: flash-style masked softmax + P@Wh ----------------
// grid (128 i-tiles, 4 j-chunks), 256 threads. Block: 64 rows x 256 cols, j range 2048.
__global__ __launch_bounds__(256, 2)
void k3_flash(const int* __restrict__ adj,
              const unsigned short* __restrict__ WhT,
              const float* __restrict__ f_src,
              const float* __restrict__ f_dst,
              const unsigned int* __restrict__ Mkey,
              float* __restrict__ Lp,
              float* __restrict__ ACC) {
    __shared__ __align__(16) unsigned short A_s[64 * 40];   // P tile [64 rows][32 k], pad 40
    __shared__ __align__(16) unsigned short B_s[256 * 40];  // Wh tile [256 cols][32 k], pad 40
    __shared__ float fd_s[2048];
    __shared__ float fs_s[64];
    __shared__ float mc_s[64];

    const int t = threadIdx.x;
    const int i0 = blockIdx.x * 64;
    const int jc = blockIdx.y;
    const int jbase = jc * 2048;

    // decode global max f_dst
    unsigned int key = *Mkey;
    union { unsigned int u; float f; } mv;
    mv.u = (key & 0x80000000u) ? (key & 0x7FFFFFFFu) : ~key;
    const float Mf = mv.f;

    if (t < 64) {
        float fs = f_src[i0 + t];
        fs_s[t] = fs;
        float v = fs + Mf;
        float m = fmaxf(v, 0.2f * v);       // leaky_relu upper bound for the row
        mc_s[t] = m * LOG2E;
    }
    {
        float4* dst = (float4*)fd_s;
        const float4* src = (const float4*)(f_dst + jbase);
        dst[t] = src[t];
        dst[256 + t] = src[256 + t];
    }
    __syncthreads();

    const int r = t >> 2;          // row 0..63 (fixed per thread)
    const int jg = t & 3;          // 8-wide j group
    const float fsr = fs_s[r];
    const float mcr = mc_s[r];
    const int* adjrow = adj + (size_t)(i0 + r) * 8192 + jbase + jg * 8;

    const int w = t >> 6, lane = t & 63, l15 = lane & 15, q = lane >> 4;
    float lsum = 0.f;

    f32x4 acc[4][4];
#pragma unroll
    for (int ri = 0; ri < 4; ++ri)
#pragma unroll
        for (int ci = 0; ci < 4; ++ci) acc[ri][ci] = (f32x4)0.0f;

    // prefetch js=0
    int4 pa0 = *(const int4*)(adjrow);
    int4 pa1 = *(const int4*)(adjrow + 4);
    uint4 pb[4];
#pragma unroll
    for (int s = 0; s < 4; ++s) {
        int id = s * 256 + t;
        int col = id >> 2, sg = id & 3;
        pb[s] = *(const uint4*)(WhT + (size_t)col * 8192 + jbase + sg * 8);
    }

    for (int js = 0; js < 64; ++js) {
        // ---- stage P (A operand layout: m=lane&15, k=quad*8+j) ----
        int av[8] = { pa0.x, pa0.y, pa0.z, pa0.w, pa1.x, pa1.y, pa1.z, pa1.w };
        const float* fdp = &fd_s[js * 32 + jg * 8];
        short8 av8;
#pragma unroll
        for (int k = 0; k < 8; ++k) {
            float tt = fsr + fdp[k];
            float e = fmaxf(tt, 0.2f * tt);
            float pe = __builtin_amdgcn_exp2f(__builtin_fmaf(e, LOG2E, -mcr));
            float p = (av[k] > 0) ? pe : 0.f;
            lsum += p;
            av8[k] = (short)f2bf(p);
        }
        *(short8*)(&A_s[r * 40 + jg * 8]) = av8;

        // ---- stage B (Wh^T tile, k-major per col) ----
#pragma unroll
        for (int s = 0; s < 4; ++s) {
            int id = s * 256 + t;
            int col = id >> 2, sg = id & 3;
            *(uint4*)(&B_s[col * 40 + sg * 8]) = pb[s];
        }
        __syncthreads();

        // ---- prefetch next js (hidden under MFMA phase) ----
        {
            int jn = (js + 1) & 63;
            pa0 = *(const int4*)(adjrow + jn * 32);
            pa1 = *(const int4*)(adjrow + jn * 32 + 4);
#pragma unroll
            for (int s = 0; s < 4; ++s) {
                int id = s * 256 + t;
                int col = id >> 2, sg = id & 3;
                pb[s] = *(const uint4*)(WhT + (size_t)col * 8192 + jbase + jn * 32 + sg * 8);
            }
        }

        // ---- MFMA: wave w owns cols w*64..w*64+63, all 64 rows ----
#pragma unroll
        for (int ri = 0; ri < 4; ++ri) {
            short8 a = *(const short8*)(&A_s[(ri * 16 + l15) * 40 + q * 8]);
#pragma unroll
            for (int ci = 0; ci < 4; ++ci) {
                short8 b = *(const short8*)(&B_s[(w * 64 + ci * 16 + l15) * 40 + q * 8]);
                acc[ri][ci] = __builtin_amdgcn_mfma_f32_16x16x32_bf16(a, b, acc[ri][ci], 0, 0, 0);
            }
        }
        __syncthreads();
    }

    // row-sum partials: combine the 4 threads (jg lanes) of each row
    lsum += __shfl_xor(lsum, 1, 64);
    lsum += __shfl_xor(lsum, 2, 64);
    if (jg == 0) Lp[jc * 8192 + i0 + r] = lsum;

    // write f32 partial accumulators
    float* accp = ACC + (size_t)jc * 2097152;
#pragma unroll
    for (int ri = 0; ri < 4; ++ri) {
#pragma unroll
        for (int ci = 0; ci < 4; ++ci) {
#pragma unroll
            for (int reg = 0; reg < 4; ++reg) {
                int grow = i0 + ri * 16 + q * 4 + reg;
                int gcol = w * 64 + ci * 16 + l15;
                accp[(size_t)grow * 256 + gcol] = acc[ri][ci][reg];
            }
        }
    }
}

// ---------------- K4: combine partials, normalize, elu, f32 out ----------------
__global__ void k4_final(const float* __restrict__ ACC,
                         const float* __restrict__ Lp,
                         float* __restrict__ out) {
    int gid = blockIdx.x * 256 + threadIdx.x;   // 524288 threads, float4 each
    int i = gid >> 6;
    float4 s = make_float4(0.f, 0.f, 0.f, 0.f);
#pragma unroll
    for (int jc = 0; jc < 4; ++jc) {
        const float4* a = (const float4*)(ACC + (size_t)jc * 2097152);
        float4 v = a[gid];
        s.x += v.x; s.y += v.y; s.z += v.z; s.w += v.w;
    }
    float L = 0.f;
#pragma unroll
    for (int jc = 0; jc < 4; ++jc) L += Lp[jc * 8192 + i];
    float inv = (L > 0.f) ? (1.0f / L) : 0.f;
    float4 o;
    {
        float h0 = s.x * inv, h1 = s.y * inv, h2 = s.z * inv, h3 = s.w * inv;
        o.x = (h0 > 0.f) ? h0 : expm1f(h0);
        o.y = (h1 > 0.f) ? h1 : expm1f(h1);
        o.z = (h2 > 0.f) ? h2 : expm1f(h2);
        o.w = (h3 > 0.f) ? h3 : expm1f(h3);
    }
    *(float4*)(out + (size_t)gid * 4) = o;
}

extern "C" void kernel_launch(void* const* d_in, const int* in_sizes, int n_in,
                              void* d_out, int out_size, void* d_ws, size_t ws_size,
                              hipStream_t stream) {
    (void)in_sizes; (void)n_in; (void)out_size; (void)ws_size;
    const float* X   = (const float*)d_in[0];   // worker_x f32 [8192][256]
    const int*   adj = (const int*)d_in[1];     // ww_adj i32 [8192][8192]
    const float* W   = (const float*)d_in[2];   // W f32 [256][256]
    const float* a_s = (const float*)d_in[3];   // a_src f32 [256]
    const float* a_d = (const float*)d_in[4];   // a_dst f32 [256]

    char* ws = (char*)d_ws;
    unsigned short* WT    = (unsigned short*)(ws + OFF_WT);
    unsigned short* WhT   = (unsigned short*)(ws + OFF_WHT);
    float*          fsrc  = (float*)(ws + OFF_FSRC);
    float*          fdst  = (float*)(ws + OFF_FDST);
    unsigned int*   Mkey  = (unsigned int*)(ws + OFF_MKEY);
    float*          Lp    = (float*)(ws + OFF_LP);
    float*          ACC   = (float*)(ws + OFF_ACC);
    float*          out   = (float*)d_out;

    k0_init<<<dim3(256), dim3(256), 0, stream>>>(W, WT, Mkey);
    k1_stage1<<<dim3(128), dim3(256), 0, stream>>>(X, WT, a_s, a_d, WhT, fsrc, fdst, Mkey);
    k3_flash<<<dim3(128, 4), dim3(256), 0, stream>>>(adj, WhT, fsrc, fdst, Mkey, Lp, ACC);
    k4_final<<<dim3(2048), dim3(256), 0, stream>>>(ACC, Lp, out);
}

// Round 3
// 593.406 us; speedup vs baseline: 1.0021x; 1.0021x over previous
//
#include <hip/hip_runtime.h>
#include <stdint.h>

typedef __attribute__((ext_vector_type(8))) short short8;
typedef __attribute__((ext_vector_type(4))) float f32x4;

#define LOG2E 1.4426950408889634f

// workspace layout (bytes)
#define OFF_WT    0u           // W^T bf16 [256][256]   = 131072
#define OFF_WHT   131072u      // Wh^T bf16 [256][8192] = 4194304
#define OFF_FSRC  4325376u     // f_src f32 [8192]
#define OFF_FDST  4358144u     // f_dst f32 [8192]
#define OFF_MKEY  4390912u     // max-key u32

__device__ __forceinline__ unsigned short f2bf(float f) {
    union { float f; unsigned int i; } v; v.f = f;
    unsigned int u = v.i;
    return (unsigned short)((u + 0x7FFFu + ((u >> 16) & 1u)) >> 16);
}

// ---------------- K0: W (f32) -> W^T (bf16), init max-key ----------------
__global__ void k0_init(const float* __restrict__ W,
                        unsigned short* __restrict__ WT,
                        unsigned int* __restrict__ Mkey) {
    int idx = blockIdx.x * 256 + threadIdx.x;   // 65536 threads
    int i = idx >> 8, o = idx & 255;
    WT[o * 256 + i] = f2bf(W[i * 256 + o]);
    if (idx == 0) *Mkey = 0u;
}

// ---------------- K1: Wh = X@W (MFMA), write Wh^T bf16, f_src/f_dst, global max f_dst ----------------
__global__ __launch_bounds__(256, 2)
void k1_stage1(const float* __restrict__ X,
               const unsigned short* __restrict__ WT,
               const float* __restrict__ a_src,
               const float* __restrict__ a_dst,
               unsigned short* __restrict__ WhT,
               float* __restrict__ f_src,
               float* __restrict__ f_dst,
               unsigned int* __restrict__ Mkey) {
    const int t = threadIdx.x;
    const int w = t >> 6, lane = t & 63, l15 = lane & 15, q = lane >> 4;
    const int rowbase = blockIdx.x * 64 + w * 16;   // wave owns 16 rows x 256 cols

    f32x4 acc[16];
#pragma unroll
    for (int ct = 0; ct < 16; ++ct) acc[ct] = (f32x4)0.0f;

#pragma unroll
    for (int ks = 0; ks < 8; ++ks) {   // K = 256 in steps of 32
        const float* xrow = X + (size_t)(rowbase + l15) * 256 + ks * 32 + q * 8;
        float4 xa = *(const float4*)(xrow);
        float4 xb = *(const float4*)(xrow + 4);
        short8 a;
        a[0] = (short)f2bf(xa.x); a[1] = (short)f2bf(xa.y);
        a[2] = (short)f2bf(xa.z); a[3] = (short)f2bf(xa.w);
        a[4] = (short)f2bf(xb.x); a[5] = (short)f2bf(xb.y);
        a[6] = (short)f2bf(xb.z); a[7] = (short)f2bf(xb.w);
#pragma unroll
        for (int ct = 0; ct < 16; ++ct) {
            short8 b = *(const short8*)(WT + (size_t)(ct * 16 + l15) * 256 + ks * 32 + q * 8);
            acc[ct] = __builtin_amdgcn_mfma_f32_16x16x32_bf16(a, b, acc[ct], 0, 0, 0);
        }
    }

    // write Wh^T bf16: C/D layout col=lane&15, row=quad*4+reg  [m89/m91]
#pragma unroll
    for (int ct = 0; ct < 16; ++ct) {
        int col = ct * 16 + l15;
        ushort4 v;
        v.x = f2bf(acc[ct][0]); v.y = f2bf(acc[ct][1]);
        v.z = f2bf(acc[ct][2]); v.w = f2bf(acc[ct][3]);
        *(ushort4*)(WhT + (size_t)col * 8192 + rowbase + q * 4) = v;
    }

    // f_src/f_dst
    float as[16], ad[16];
#pragma unroll
    for (int ct = 0; ct < 16; ++ct) {
        as[ct] = a_src[ct * 16 + l15];
        ad[ct] = a_dst[ct * 16 + l15];
    }
#pragma unroll
    for (int reg = 0; reg < 4; ++reg) {
        float ps = 0.f, pd = 0.f;
#pragma unroll
        for (int ct = 0; ct < 16; ++ct) {
            ps += acc[ct][reg] * as[ct];
            pd += acc[ct][reg] * ad[ct];
        }
#pragma unroll
        for (int m = 1; m < 16; m <<= 1) {
            ps += __shfl_xor(ps, m, 64);
            pd += __shfl_xor(pd, m, 64);
        }
        if (l15 == 0) {
            int row = rowbase + q * 4 + reg;
            f_src[row] = ps;
            f_dst[row] = pd;
            union { float f; unsigned int u; } cv; cv.f = pd;
            unsigned int key = (cv.u & 0x80000000u) ? ~cv.u : (cv.u | 0x80000000u);
            atomicMax(Mkey, key);
        }
    }
}

// ---------------- K2: barrier-free full-K fused GAT kernel ----------------
// Block: 32 rows x 256 cols, 512 threads = 8 waves, each wave K-chunk of 1024.
// Per lane: computes its own A-fragment P values in registers (no LDS, no
// barriers in the K-loop). B-frags read from global WhT (L2-resident).
// End: single-barrier LDS ds_add_f32 reduction + fused normalize/ELU store.
__global__ __launch_bounds__(512, 2)
void k2_fused(const int* __restrict__ adj,
              const unsigned short* __restrict__ WhT,
              const float* __restrict__ f_src,
              const float* __restrict__ f_dst,
              const unsigned int* __restrict__ Mkey,
              float* __restrict__ out) {
    __shared__ float red[32 * 256];   // 32 KB reduction tile
    __shared__ float Lrow[32];

    const int t = threadIdx.x;
    const int w = t >> 6, lane = t & 63, l15 = lane & 15, q = lane >> 4;
    const int i0 = blockIdx.x * 32;

    // zero reduction buffers (poisoned 0xAA by harness)
    {
        float4* p = (float4*)red;
#pragma unroll
        for (int s = 0; s < 4; ++s) p[s * 512 + t] = make_float4(0.f, 0.f, 0.f, 0.f);
        if (t < 32) Lrow[t] = 0.f;
    }
    __syncthreads();

    // decode global max f_dst
    unsigned int key = *Mkey;
    union { unsigned int u; float f; } mv;
    mv.u = (key & 0x80000000u) ? (key & 0x7FFFFFFFu) : ~key;
    const float Mf = mv.f;

    const float fsA = f_src[i0 + l15];
    const float fsB = f_src[i0 + 16 + l15];
    float vA = fsA + Mf; const float mcA = fmaxf(vA, 0.2f * vA) * LOG2E;
    float vB = fsB + Mf; const float mcB = fmaxf(vB, 0.2f * vB) * LOG2E;

    const int kb = w * 1024 + q * 8;   // wave k-chunk + lane k-offset
    const int* adjA = adj + (size_t)(i0 + l15) * 8192 + kb;
    const int* adjB = adj + (size_t)(i0 + 16 + l15) * 8192 + kb;
    const float* fdp = f_dst + kb;
    const unsigned short* Bp = WhT + (size_t)l15 * 8192 + kb;   // + ci*131072 + js*32

    f32x4 accA[16], accB[16];
#pragma unroll
    for (int ci = 0; ci < 16; ++ci) { accA[ci] = (f32x4)0.0f; accB[ci] = (f32x4)0.0f; }
    float lsA = 0.f, lsB = 0.f;

    // prefetch js=0
    int4 pA0 = *(const int4*)(adjA);
    int4 pA1 = *(const int4*)(adjA + 4);
    int4 pB0 = *(const int4*)(adjB);
    int4 pB1 = *(const int4*)(adjB + 4);
    float4 pf0 = *(const float4*)(fdp);
    float4 pf1 = *(const float4*)(fdp + 4);
    short8 Bf[8];
#pragma unroll
    for (int ci = 0; ci < 8; ++ci)
        Bf[ci] = *(const short8*)(Bp + (size_t)ci * 131072);

    for (int js = 0; js < 32; ++js) {
        // ---- P compute from prefetched regs: A-frag A[m=l15][k=q*8+j] ----
        float fdv[8] = { pf0.x, pf0.y, pf0.z, pf0.w, pf1.x, pf1.y, pf1.z, pf1.w };
        int aAv[8] = { pA0.x, pA0.y, pA0.z, pA0.w, pA1.x, pA1.y, pA1.z, pA1.w };
        int aBv[8] = { pB0.x, pB0.y, pB0.z, pB0.w, pB1.x, pB1.y, pB1.z, pB1.w };
        short8 fragA, fragB;
#pragma unroll
        for (int k = 0; k < 8; ++k) {
            float tA = fsA + fdv[k];
            float eA = fmaxf(tA, 0.2f * tA);
            float pAx = __builtin_amdgcn_exp2f(__builtin_fmaf(eA, LOG2E, -mcA));
            pAx = (aAv[k] > 0) ? pAx : 0.f;
            lsA += pAx;
            fragA[k] = (short)f2bf(pAx);
            float tB = fsB + fdv[k];
            float eB = fmaxf(tB, 0.2f * tB);
            float pBx = __builtin_amdgcn_exp2f(__builtin_fmaf(eB, LOG2E, -mcB));
            pBx = (aBv[k] > 0) ? pBx : 0.f;
            lsB += pBx;
            fragB[k] = (short)f2bf(pBx);
        }

        // ---- prefetch next iter adj/fd (longest distance, HBM latency) ----
        int jn = (js + 1) & 31;
        pA0 = *(const int4*)(adjA + jn * 32);
        pA1 = *(const int4*)(adjA + jn * 32 + 4);
        pB0 = *(const int4*)(adjB + jn * 32);
        pB1 = *(const int4*)(adjB + jn * 32 + 4);
        pf0 = *(const float4*)(fdp + jn * 32);
        pf1 = *(const float4*)(fdp + jn * 32 + 4);

        // ---- MFMA ci 0-7 (Bf = (js, ci0-7)) ----
#pragma unroll
        for (int ci = 0; ci < 8; ++ci) {
            accA[ci] = __builtin_amdgcn_mfma_f32_16x16x32_bf16(fragA, Bf[ci], accA[ci], 0, 0, 0);
            accB[ci] = __builtin_amdgcn_mfma_f32_16x16x32_bf16(fragB, Bf[ci], accB[ci], 0, 0, 0);
        }
        // ---- load Bf <- (js, ci 8-15), hidden under MFMA drain ----
#pragma unroll
        for (int ci = 0; ci < 8; ++ci)
            Bf[ci] = *(const short8*)(Bp + (size_t)(ci + 8) * 131072 + js * 32);
        // ---- MFMA ci 8-15 ----
#pragma unroll
        for (int ci = 0; ci < 8; ++ci) {
            accA[8 + ci] = __builtin_amdgcn_mfma_f32_16x16x32_bf16(fragA, Bf[ci], accA[8 + ci], 0, 0, 0);
            accB[8 + ci] = __builtin_amdgcn_mfma_f32_16x16x32_bf16(fragB, Bf[ci], accB[8 + ci], 0, 0, 0);
        }
        // ---- load Bf <- (js+1, ci 0-7) ----
#pragma unroll
        for (int ci = 0; ci < 8; ++ci)
            Bf[ci] = *(const short8*)(Bp + (size_t)ci * 131072 + jn * 32);
    }

    // ---- row-sum partials: quads of same l15 hold disjoint k; reduce, then LDS atomic across waves ----
    lsA += __shfl_xor(lsA, 16, 64); lsA += __shfl_xor(lsA, 32, 64);
    lsB += __shfl_xor(lsB, 16, 64); lsB += __shfl_xor(lsB, 32, 64);
    if (q == 0) {
        atomicAdd(&Lrow[l15], lsA);
        atomicAdd(&Lrow[16 + l15], lsB);
    }

    // ---- accumulate wave-partial tiles into LDS (ds_add_f32) ----
    // C/D layout: row = q*4+reg, col = ci*16+l15
#pragma unroll
    for (int ci = 0; ci < 16; ++ci) {
#pragma unroll
        for (int reg = 0; reg < 4; ++reg) {
            atomicAdd(&red[(q * 4 + reg) * 256 + ci * 16 + l15], accA[ci][reg]);
            atomicAdd(&red[(16 + q * 4 + reg) * 256 + ci * 16 + l15], accB[ci][reg]);
        }
    }
    __syncthreads();

    // ---- epilogue: normalize, ELU, store f32 (16 elems/thread) ----
    {
        int row = t >> 4, cb = (t & 15) * 16;
        float L = Lrow[row];
        float inv = (L > 0.f) ? (1.0f / L) : 0.f;
        const float* rp = &red[row * 256 + cb];
        float* op = out + (size_t)(i0 + row) * 256 + cb;
#pragma unroll
        for (int v = 0; v < 4; ++v) {
            float4 x = *(const float4*)(rp + v * 4);
            float4 o;
            float h0 = x.x * inv, h1 = x.y * inv, h2 = x.z * inv, h3 = x.w * inv;
            o.x = (h0 > 0.f) ? h0 : expm1f(h0);
            o.y = (h1 > 0.f) ? h1 : expm1f(h1);
            o.z = (h2 > 0.f) ? h2 : expm1f(h2);
            o.w = (h3 > 0.f) ? h3 : expm1f(h3);
            *(float4*)(op + v * 4) = o;
        }
    }
}

extern "C" void kernel_launch(void* const* d_in, const int* in_sizes, int n_in,
                              void* d_out, int out_size, void* d_ws, size_t ws_size,
                              hipStream_t stream) {
    (void)in_sizes; (void)n_in; (void)out_size; (void)ws_size;
    const float* X   = (const float*)d_in[0];   // worker_x f32 [8192][256]
    const int*   adj = (const int*)d_in[1];     // ww_adj i32 [8192][8192]
    const float* W   = (const float*)d_in[2];   // W f32 [256][256]
    const float* a_s = (const float*)d_in[3];   // a_src f32 [256]
    const float* a_d = (const float*)d_in[4];   // a_dst f32 [256]

    char* ws = (char*)d_ws;
    unsigned short* WT   = (unsigned short*)(ws + OFF_WT);
    unsigned short* WhT  = (unsigned short*)(ws + OFF_WHT);
    float*          fsrc = (float*)(ws + OFF_FSRC);
    float*          fdst = (float*)(ws + OFF_FDST);
    unsigned int*   Mkey = (unsigned int*)(ws + OFF_MKEY);
    float*          out  = (float*)d_out;

    k0_init<<<dim3(256), dim3(256), 0, stream>>>(W, WT, Mkey);
    k1_stage1<<<dim3(128), dim3(256), 0, stream>>>(X, WT, a_s, a_d, WhT, fsrc, fdst, Mkey);
    k2_fused<<<dim3(256), dim3(512), 0, stream>>>(adj, WhT, fsrc, fdst, Mkey, out);
}

// Round 4
// 487.241 us; speedup vs baseline: 1.2204x; 1.2179x over previous
//
#include <hip/hip_runtime.h>
#include <stdint.h>

typedef __attribute__((ext_vector_type(8))) short short8;
typedef __attribute__((ext_vector_type(4))) float f32x4;
typedef __attribute__((ext_vector_type(4))) _Float16 h16x4;

#define LOG2E 1.4426950408889634f

// workspace layout (bytes)
#define OFF_WTT   0u          // W tiled bf16 [8][4][256][8]        = 131072
#define OFF_WHTB  131072u     // Wh tiled bf16 [256][4][256][8]     = 4194304
#define OFF_BITS  4325376u    // adj bitmask u32 [8192][256]        = 8388608
#define OFF_FSRC  12713984u   // f_src f32 [8192]                   = 32768
#define OFF_FDST  12746752u   // f_dst f32 [8192]                   = 32768
#define OFF_MKEY  12779520u   // max-key u32                        = 64
#define OFF_LP    12779584u   // L partials f32 [4][8192]           = 131072
#define OFF_ACCH  12910656u   // ACC partials f16 [4][8192][256]    = 16777216
// total = 29,687,872 bytes  (proven ws >= 38 MB in R2/R3)

__device__ __forceinline__ unsigned short f2bf(float f) {
    union { float f; unsigned int i; } v; v.f = f;
    unsigned int u = v.i;
    return (unsigned short)((u + 0x7FFFu + ((u >> 16) & 1u)) >> 16);
}

// tiled index for a [K][256] -> [kblk][sub][col][8] bf16 matrix (k = row dim)
// flat = (k>>5)*8192 + ((k>>3)&3)*2048 + col*8 + (k&7)

// ---------------- K0: W (f32) -> tiled W^T (bf16), init max-key ----------------
__global__ void k0_init(const float* __restrict__ W,
                        unsigned short* __restrict__ WTt,
                        unsigned int* __restrict__ Mkey) {
    int idx = blockIdx.x * 256 + threadIdx.x;   // 65536 = i*256+o
    int i = idx >> 8, o = idx & 255;            // i = k-dim (in_dim), o = col (out_dim)
    WTt[(i >> 5) * 8192 + ((i >> 3) & 3) * 2048 + o * 8 + (i & 7)] = f2bf(W[idx]);
    if (idx == 0) *Mkey = 0u;
}

// ---------------- K_pack: adj int32 -> bitmask (perfectly coalesced stream) ----
// wave packs 256 consecutive ints -> 8 u32 words via shfl tree. bit b of word w
// (window base j0) = adj[j0 + 32w + b].
__global__ __launch_bounds__(256, 4)
void k_pack(const int* __restrict__ adj, unsigned int* __restrict__ bits) {
    int wave_id = (blockIdx.x * 256 + threadIdx.x) >> 6;   // 0..4095
    int lane = threadIdx.x & 63;
#pragma unroll 2
    for (int it = 0; it < 64; ++it) {
        size_t win = (size_t)wave_id * 64 + it;            // 256 ints per window
        int4 v = *(const int4*)(adj + win * 256 + lane * 4);
        unsigned int nib = (v.x > 0 ? 1u : 0u) | (v.y > 0 ? 2u : 0u) |
                           (v.z > 0 ? 4u : 0u) | (v.w > 0 ? 8u : 0u);
        unsigned int s;
        s = __shfl_xor(nib, 1, 64);  nib = (lane & 1) ? (s | (nib << 4))  : (nib | (s << 4));
        s = __shfl_xor(nib, 2, 64);  nib = (lane & 2) ? (s | (nib << 8))  : (nib | (s << 8));
        s = __shfl_xor(nib, 4, 64);  nib = (lane & 4) ? (s | (nib << 16)) : (nib | (s << 16));
        if ((lane & 7) == 0) bits[win * 8 + (lane >> 3)] = nib;
    }
}

// ---------------- K1: Wh = X@W, write tiled Wh (bf16), f_src/f_dst, global max ----
// grid 256, block 256 (4 waves): rg=w&1 (16 rows), cg=w>>1 (128 cols). 32 rows/block.
__global__ __launch_bounds__(256, 2)
void k1_stage1(const float* __restrict__ X,
               const unsigned short* __restrict__ WTt,
               const float* __restrict__ a_src,
               const float* __restrict__ a_dst,
               unsigned short* __restrict__ WhTb,
               float* __restrict__ f_src,
               float* __restrict__ f_dst,
               unsigned int* __restrict__ Mkey) {
    __shared__ __align__(16) unsigned short Bt[8192];   // 16 KB tile
    __shared__ float fsum[64];
    const int t = threadIdx.x, w = t >> 6, lane = t & 63, l15 = lane & 15, q = lane >> 4;
    const int rg = w & 1, cg = w >> 1;
    const int i0 = blockIdx.x * 32;
    const int arow = i0 + rg * 16 + l15;

    if (t < 64) fsum[t] = 0.f;

    float as[8], ad[8];
#pragma unroll
    for (int ci = 0; ci < 8; ++ci) {
        int col = cg * 128 + ci * 16 + l15;
        as[ci] = a_src[col]; ad[ci] = a_dst[col];
    }

    f32x4 acc[8];
#pragma unroll
    for (int ci = 0; ci < 8; ++ci) acc[ci] = (f32x4)0.f;

    for (int ks = 0; ks < 8; ++ks) {
        __syncthreads();    // protect Bt (also covers fsum zero on first iter)
        {   // stage contiguous 16 KB slice: fully coalesced
            const uint4* src = (const uint4*)(WTt + ks * 8192);
            uint4* dst = (uint4*)Bt;
            dst[t] = src[t]; dst[256 + t] = src[256 + t];
            dst[512 + t] = src[512 + t]; dst[768 + t] = src[768 + t];
        }
        __syncthreads();
        // A-frag: X row, k = ks*32 + q*8 + j
        const float* xp = X + (size_t)arow * 256 + ks * 32 + q * 8;
        float4 xa = *(const float4*)xp;
        float4 xb = *(const float4*)(xp + 4);
        short8 a;
        a[0] = (short)f2bf(xa.x); a[1] = (short)f2bf(xa.y);
        a[2] = (short)f2bf(xa.z); a[3] = (short)f2bf(xa.w);
        a[4] = (short)f2bf(xb.x); a[5] = (short)f2bf(xb.y);
        a[6] = (short)f2bf(xb.z); a[7] = (short)f2bf(xb.w);
#pragma unroll
        for (int ci = 0; ci < 8; ++ci) {
            short8 b = *(const short8*)((const char*)Bt + q * 4096 + (cg * 128 + ci * 16 + l15) * 16);
            acc[ci] = __builtin_amdgcn_mfma_f32_16x16x32_bf16(a, b, acc[ci], 0, 0, 0);
        }
    }

    // write tiled Wh: C/D layout col=lane&15, j-row=q*4+reg
#pragma unroll
    for (int ci = 0; ci < 8; ++ci) {
        int col = cg * 128 + ci * 16 + l15;
        ushort4 v;
        v.x = f2bf(acc[ci][0]); v.y = f2bf(acc[ci][1]);
        v.z = f2bf(acc[ci][2]); v.w = f2bf(acc[ci][3]);
        size_t flat = (size_t)(i0 >> 5) * 8192 + (size_t)(rg * 2 + (q >> 1)) * 2048
                      + (size_t)col * 8 + (q & 1) * 4;
        *(ushort4*)(WhTb + flat) = v;
    }

    // f_src / f_dst partials (each wave covers 128 cols; 2 cg waves add via LDS)
#pragma unroll
    for (int reg = 0; reg < 4; ++reg) {
        float ps = 0.f, pd = 0.f;
#pragma unroll
        for (int ci = 0; ci < 8; ++ci) {
            ps += acc[ci][reg] * as[ci];
            pd += acc[ci][reg] * ad[ci];
        }
#pragma unroll
        for (int m = 1; m < 16; m <<= 1) {
            ps += __shfl_xor(ps, m, 64);
            pd += __shfl_xor(pd, m, 64);
        }
        if (l15 == 0) {
            atomicAdd(&fsum[rg * 16 + q * 4 + reg], ps);
            atomicAdd(&fsum[32 + rg * 16 + q * 4 + reg], pd);
        }
    }
    __syncthreads();
    if (t < 32) {
        int row = i0 + t;
        float ps = fsum[t], pd = fsum[32 + t];
        f_src[row] = ps;
        f_dst[row] = pd;
        union { float f; unsigned int u; } cv; cv.f = pd;
        unsigned int key = (cv.u & 0x80000000u) ? ~cv.u : (cv.u | 0x80000000u);
        atomicMax(Mkey, key);
    }
}

// ---------------- K2: fused masked-softmax + P@Wh ----------------
// grid (64 i-tiles x 4 j-chunks), 512 thr = 8 waves: rg=w>>1 (32 rows), cg=w&1 (128 cols).
// Double-buffered contiguous 16 KB B tiles; P computed in registers (A-frag layout);
// adjacency from bitmask; f16 split-j partials.
__global__ __launch_bounds__(512, 2)
void k2_flash(const unsigned int* __restrict__ BITS,
              const unsigned short* __restrict__ WhTb,
              const float* __restrict__ f_src,
              const float* __restrict__ f_dst,
              const unsigned int* __restrict__ Mkey,
              float* __restrict__ Lp,
              _Float16* __restrict__ ACCh) {
    __shared__ __align__(16) unsigned short Bt[2][8192];   // 2 x 16 KB
    __shared__ float fd_s[2048];                           // 8 KB
    const int t = threadIdx.x, w = t >> 6, lane = t & 63, l15 = lane & 15, q = lane >> 4;
    const int rg = w >> 1, cg = w & 1;
    const int i0 = blockIdx.x * 128;
    const int jc = blockIdx.y;
    const int jb0 = jc * 2048, jw0 = jc * 64;
    const int rA = i0 + rg * 32 + l15, rB = rA + 16;

    unsigned int key = *Mkey;
    union { unsigned int u; float f; } mv;
    mv.u = (key & 0x80000000u) ? (key & 0x7FFFFFFFu) : ~key;
    const float Mf = mv.f;
    const float fsA = f_src[rA], fsB = f_src[rB];
    float vA = fsA + Mf; const float mcA = fmaxf(vA, 0.2f * vA) * LOG2E;
    float vB = fsB + Mf; const float mcB = fmaxf(vB, 0.2f * vB) * LOG2E;

    // stage fd chunk + tile 0 (coalesced)
    { float4* d = (float4*)fd_s; d[t] = *(const float4*)(f_dst + jb0 + t * 4); }
    {
        const uint4* src = (const uint4*)(WhTb + (size_t)jw0 * 8192);
        uint4* dst = (uint4*)&Bt[0][0];
        dst[t] = src[t]; dst[512 + t] = src[512 + t];
    }
    const unsigned int* bpA = BITS + (size_t)rA * 256 + jw0;
    const unsigned int* bpB = BITS + (size_t)rB * 256 + jw0;
    unsigned int pwA = bpA[0], pwB = bpB[0];

    f32x4 accA[8], accB[8];
#pragma unroll
    for (int ci = 0; ci < 8; ++ci) { accA[ci] = (f32x4)0.f; accB[ci] = (f32x4)0.f; }
    float lsA = 0.f, lsB = 0.f;
    __syncthreads();

    for (int js = 0; js < 64; ++js) {
        const int buf = js & 1;
        const int jn = (js + 1) & 63;   // wrap on last iter: harmless redundant work
        // issue next-tile + next-bits loads (consumed after MFMA section)
        const uint4* nsrc = (const uint4*)(WhTb + (size_t)(jw0 + jn) * 8192);
        uint4 g0 = nsrc[t];
        uint4 g1 = nsrc[512 + t];
        unsigned int nwA = bpA[jn], nwB = bpB[jn];

        // fd fragment (LDS broadcast)
        const float* fdp = fd_s + js * 32 + q * 8;
        float4 f0 = *(const float4*)fdp, f1 = *(const float4*)(fdp + 4);
        float fdv[8] = { f0.x, f0.y, f0.z, f0.w, f1.x, f1.y, f1.z, f1.w };

        // P fragments in A-operand layout: A[m=l15][k=q*8+j]
        unsigned int bA = pwA >> (q * 8), bB = pwB >> (q * 8);
        short8 fragA, fragB;
#pragma unroll
        for (int k = 0; k < 8; ++k) {
            float tA = fsA + fdv[k];
            float eA = fmaxf(tA, 0.2f * tA);
            float pA = __builtin_amdgcn_exp2f(__builtin_fmaf(eA, LOG2E, -mcA));
            pA = ((bA >> k) & 1u) ? pA : 0.f;
            lsA += pA; fragA[k] = (short)f2bf(pA);
            float tB = fsB + fdv[k];
            float eB = fmaxf(tB, 0.2f * tB);
            float pB = __builtin_amdgcn_exp2f(__builtin_fmaf(eB, LOG2E, -mcB));
            pB = ((bB >> k) & 1u) ? pB : 0.f;
            lsB += pB; fragB[k] = (short)f2bf(pB);
        }

        // MFMA on current buffer (conflict-free ds_read_b128, 2-way aliasing only)
        const char* base = (const char*)&Bt[buf][0] + q * 4096 + (cg * 128 + l15) * 16;
#pragma unroll
        for (int ci = 0; ci < 8; ++ci) {
            short8 bf = *(const short8*)(base + ci * 256);
            accA[ci] = __builtin_amdgcn_mfma_f32_16x16x32_bf16(fragA, bf, accA[ci], 0, 0, 0);
            accB[ci] = __builtin_amdgcn_mfma_f32_16x16x32_bf16(fragB, bf, accB[ci], 0, 0, 0);
        }

        // write next tile into other buffer (vmcnt wait lands after MFMAs issued)
        { uint4* dst = (uint4*)&Bt[buf ^ 1][0]; dst[t] = g0; dst[512 + t] = g1; }
        pwA = nwA; pwB = nwB;
        __syncthreads();
    }

    // row-sums: combine 4 quads; only cg=0 counts (cg=1 duplicates P)
    lsA += __shfl_xor(lsA, 16, 64); lsA += __shfl_xor(lsA, 32, 64);
    lsB += __shfl_xor(lsB, 16, 64); lsB += __shfl_xor(lsB, 32, 64);
    if (cg == 0 && q == 0) {
        Lp[(size_t)jc * 8192 + i0 + rg * 32 + l15] = lsA;
        Lp[(size_t)jc * 8192 + i0 + rg * 32 + 16 + l15] = lsB;
    }

    // f16 split-j partials
    _Float16* ap = ACCh + (size_t)jc * 2097152;
#pragma unroll
    for (int ci = 0; ci < 8; ++ci) {
        int col = cg * 128 + ci * 16 + l15;
#pragma unroll
        for (int reg = 0; reg < 4; ++reg) {
            int rowA = i0 + rg * 32 + q * 4 + reg;
            ap[(size_t)rowA * 256 + col] = (_Float16)accA[ci][reg];
            ap[(size_t)(rowA + 16) * 256 + col] = (_Float16)accB[ci][reg];
        }
    }
}

// ---------------- K4: combine partials, normalize, elu, f32 out ----------------
__global__ void k4_final(const _Float16* __restrict__ ACCh,
                         const float* __restrict__ Lp,
                         float* __restrict__ out) {
    int gid = blockIdx.x * 256 + threadIdx.x;   // 524288 threads x 4 elems
    int i = gid >> 6;
    float s0 = 0.f, s1 = 0.f, s2 = 0.f, s3 = 0.f;
#pragma unroll
    for (int jc = 0; jc < 4; ++jc) {
        h16x4 v = *(const h16x4*)(ACCh + (size_t)jc * 2097152 + (size_t)gid * 4);
        s0 += (float)v[0]; s1 += (float)v[1]; s2 += (float)v[2]; s3 += (float)v[3];
    }
    float L = 0.f;
#pragma unroll
    for (int jc = 0; jc < 4; ++jc) L += Lp[jc * 8192 + i];
    float inv = (L > 0.f) ? (1.0f / L) : 0.f;
    float h0 = s0 * inv, h1 = s1 * inv, h2 = s2 * inv, h3 = s3 * inv;
    float4 o;
    o.x = (h0 > 0.f) ? h0 : expm1f(h0);
    o.y = (h1 > 0.f) ? h1 : expm1f(h1);
    o.z = (h2 > 0.f) ? h2 : expm1f(h2);
    o.w = (h3 > 0.f) ? h3 : expm1f(h3);
    *(float4*)(out + (size_t)gid * 4) = o;
}

extern "C" void kernel_launch(void* const* d_in, const int* in_sizes, int n_in,
                              void* d_out, int out_size, void* d_ws, size_t ws_size,
                              hipStream_t stream) {
    (void)in_sizes; (void)n_in; (void)out_size; (void)ws_size;
    const float* X   = (const float*)d_in[0];   // worker_x f32 [8192][256]
    const int*   adj = (const int*)d_in[1];     // ww_adj i32 [8192][8192]
    const float* W   = (const float*)d_in[2];   // W f32 [256][256]
    const float* a_s = (const float*)d_in[3];   // a_src f32 [256]
    const float* a_d = (const float*)d_in[4];   // a_dst f32 [256]

    char* ws = (char*)d_ws;
    unsigned short* WTt  = (unsigned short*)(ws + OFF_WTT);
    unsigned short* WhTb = (unsigned short*)(ws + OFF_WHTB);
    unsigned int*   BITS = (unsigned int*)(ws + OFF_BITS);
    float*          fsrc = (float*)(ws + OFF_FSRC);
    float*          fdst = (float*)(ws + OFF_FDST);
    unsigned int*   Mkey = (unsigned int*)(ws + OFF_MKEY);
    float*          Lp   = (float*)(ws + OFF_LP);
    _Float16*       ACCh = (_Float16*)(ws + OFF_ACCH);
    float*          out  = (float*)d_out;

    k0_init<<<dim3(256), dim3(256), 0, stream>>>(W, WTt, Mkey);
    k_pack<<<dim3(1024), dim3(256), 0, stream>>>(adj, BITS);
    k1_stage1<<<dim3(256), dim3(256), 0, stream>>>(X, WTt, a_s, a_d, WhTb, fsrc, fdst, Mkey);
    k2_flash<<<dim3(64, 4), dim3(512), 0, stream>>>(BITS, WhTb, fsrc, fdst, Mkey, Lp, ACCh);
    k4_final<<<dim3(2048), dim3(256), 0, stream>>>(ACCh, Lp, out);
}

// Round 5
// 459.373 us; speedup vs baseline: 1.2944x; 1.0607x over previous
//
#include <hip/hip_runtime.h>
#include <stdint.h>

typedef __attribute__((ext_vector_type(8))) short short8;
typedef __attribute__((ext_vector_type(4))) float f32x4;
typedef __attribute__((ext_vector_type(4))) _Float16 h16x4;

#define LOG2E 1.4426950408889634f

// workspace layout (bytes)
#define OFF_WTT   0u          // W tiled bf16 [8][4][256][8]        = 131072
#define OFF_WHTB  131072u     // Wh tiled bf16 [256][4][256][8]     = 4194304
#define OFF_BITS  4325376u    // adj bitmask u64 [8192][128]        = 8388608
#define OFF_FSRC  12713984u   // f_src f32 [8192]                   = 32768
#define OFF_FDST  12746752u   // f_dst f32 [8192]                   = 32768
#define OFF_MKEY  12779520u   // max-key u32                        = 64
#define OFF_LP    12779584u   // L partials f32 [4][8192]           = 131072
#define OFF_ACCH  12910656u   // ACC partials f16 [4][8192][256]    = 16777216
// total = 29,687,872 bytes

__device__ __forceinline__ unsigned short f2bf(float f) {
    union { float f; unsigned int i; } v; v.f = f;
    unsigned int u = v.i;
    return (unsigned short)((u + 0x7FFFu + ((u >> 16) & 1u)) >> 16);
}

// ---------------- K0: W (f32) -> tiled W^T (bf16), init max-key ----------------
__global__ void k0_init(const float* __restrict__ W,
                        unsigned short* __restrict__ WTt,
                        unsigned int* __restrict__ Mkey) {
    int idx = blockIdx.x * 256 + threadIdx.x;   // 65536 = i*256+o
    int i = idx >> 8, o = idx & 255;
    WTt[(i >> 5) * 8192 + ((i >> 3) & 3) * 2048 + o * 8 + (i & 7)] = f2bf(W[idx]);
    if (idx == 0) *Mkey = 0u;
}

// ---------------- K_pack: adj int32 -> bitmask via ballot (streaming) ----------
// wave owns 16384 contiguous ints; per iter: coalesced 4B/lane load, ballot
// gives the 64-int mask in lane order. Unroll 8 => 8 outstanding loads/wave.
__global__ __launch_bounds__(256, 8)
void k_pack(const int* __restrict__ adj, unsigned long long* __restrict__ bits64) {
    int wave_id = (blockIdx.x * 256 + threadIdx.x) >> 6;   // 0..4095
    int lane = threadIdx.x & 63;
    const int* p = adj + (size_t)wave_id * 16384 + lane;
    unsigned long long* bp = bits64 + (size_t)wave_id * 256;
    for (int it = 0; it < 256; it += 8) {
        int v[8];
#pragma unroll
        for (int u = 0; u < 8; ++u) v[u] = p[(size_t)(it + u) * 64];
#pragma unroll
        for (int u = 0; u < 8; ++u) {
            unsigned long long m = __ballot(v[u] > 0);
            if (lane == 0) bp[it + u] = m;
        }
    }
}

// ---------------- K1: Wh = X@W, write tiled Wh (bf16), f_src/f_dst, global max ----
__global__ __launch_bounds__(256, 2)
void k1_stage1(const float* __restrict__ X,
               const unsigned short* __restrict__ WTt,
               const float* __restrict__ a_src,
               const float* __restrict__ a_dst,
               unsigned short* __restrict__ WhTb,
               float* __restrict__ f_src,
               float* __restrict__ f_dst,
               unsigned int* __restrict__ Mkey) {
    __shared__ __align__(16) unsigned short Bt[8192];   // 16 KB tile
    __shared__ float fsum[64];
    const int t = threadIdx.x, w = t >> 6, lane = t & 63, l15 = lane & 15, q = lane >> 4;
    const int rg = w & 1, cg = w >> 1;
    const int i0 = blockIdx.x * 32;
    const int arow = i0 + rg * 16 + l15;

    if (t < 64) fsum[t] = 0.f;

    float as[8], ad[8];
#pragma unroll
    for (int ci = 0; ci < 8; ++ci) {
        int col = cg * 128 + ci * 16 + l15;
        as[ci] = a_src[col]; ad[ci] = a_dst[col];
    }

    f32x4 acc[8];
#pragma unroll
    for (int ci = 0; ci < 8; ++ci) acc[ci] = (f32x4)0.f;

    for (int ks = 0; ks < 8; ++ks) {
        __syncthreads();
        {
            const uint4* src = (const uint4*)(WTt + ks * 8192);
            uint4* dst = (uint4*)Bt;
            dst[t] = src[t]; dst[256 + t] = src[256 + t];
            dst[512 + t] = src[512 + t]; dst[768 + t] = src[768 + t];
        }
        __syncthreads();
        const float* xp = X + (size_t)arow * 256 + ks * 32 + q * 8;
        float4 xa = *(const float4*)xp;
        float4 xb = *(const float4*)(xp + 4);
        short8 a;
        a[0] = (short)f2bf(xa.x); a[1] = (short)f2bf(xa.y);
        a[2] = (short)f2bf(xa.z); a[3] = (short)f2bf(xa.w);
        a[4] = (short)f2bf(xb.x); a[5] = (short)f2bf(xb.y);
        a[6] = (short)f2bf(xb.z); a[7] = (short)f2bf(xb.w);
#pragma unroll
        for (int ci = 0; ci < 8; ++ci) {
            short8 b = *(const short8*)((const char*)Bt + q * 4096 + (cg * 128 + ci * 16 + l15) * 16);
            acc[ci] = __builtin_amdgcn_mfma_f32_16x16x32_bf16(a, b, acc[ci], 0, 0, 0);
        }
    }

#pragma unroll
    for (int ci = 0; ci < 8; ++ci) {
        int col = cg * 128 + ci * 16 + l15;
        ushort4 v;
        v.x = f2bf(acc[ci][0]); v.y = f2bf(acc[ci][1]);
        v.z = f2bf(acc[ci][2]); v.w = f2bf(acc[ci][3]);
        size_t flat = (size_t)(i0 >> 5) * 8192 + (size_t)(rg * 2 + (q >> 1)) * 2048
                      + (size_t)col * 8 + (q & 1) * 4;
        *(ushort4*)(WhTb + flat) = v;
    }

#pragma unroll
    for (int reg = 0; reg < 4; ++reg) {
        float ps = 0.f, pd = 0.f;
#pragma unroll
        for (int ci = 0; ci < 8; ++ci) {
            ps += acc[ci][reg] * as[ci];
            pd += acc[ci][reg] * ad[ci];
        }
#pragma unroll
        for (int m = 1; m < 16; m <<= 1) {
            ps += __shfl_xor(ps, m, 64);
            pd += __shfl_xor(pd, m, 64);
        }
        if (l15 == 0) {
            atomicAdd(&fsum[rg * 16 + q * 4 + reg], ps);
            atomicAdd(&fsum[32 + rg * 16 + q * 4 + reg], pd);
        }
    }
    __syncthreads();
    if (t < 32) {
        int row = i0 + t;
        float ps = fsum[t], pd = fsum[32 + t];
        f_src[row] = ps;
        f_dst[row] = pd;
        union { float f; unsigned int u; } cv; cv.f = pd;
        unsigned int key = (cv.u & 0x80000000u) ? ~cv.u : (cv.u | 0x80000000u);
        atomicMax(Mkey, key);
    }
}

// ---------------- K2: fused masked-softmax + P@Wh ----------------
// grid (128 i-tiles x 4 j-chunks), 256 thr = 4 waves; wave = 16 rows x 256 cols
// (no P duplication). Double-buffered 16 KB B tile; one barrier/iter; up to
// 4 blocks/CU (LDS 40 KB, VGPR<=128) so barriers overlap across blocks.
__global__ __launch_bounds__(256, 4)
void k2_flash(const unsigned int* __restrict__ BITS,
              const unsigned short* __restrict__ WhTb,
              const float* __restrict__ f_src,
              const float* __restrict__ f_dst,
              const unsigned int* __restrict__ Mkey,
              float* __restrict__ Lp,
              _Float16* __restrict__ ACCh) {
    __shared__ __align__(16) unsigned short Bt[2][8192];   // 32 KB
    __shared__ float fd_s[2048];                           // 8 KB
    const int t = threadIdx.x, w = t >> 6, lane = t & 63, l15 = lane & 15, q = lane >> 4;
    const int i0 = blockIdx.x * 64;
    const int jc = blockIdx.y;
    const int jb0 = jc * 2048, jw0 = jc * 64;
    const int rA = i0 + w * 16 + l15;

    unsigned int key = *Mkey;
    union { unsigned int u; float f; } mv;
    mv.u = (key & 0x80000000u) ? (key & 0x7FFFFFFFu) : ~key;
    const float Mf = mv.f;
    const float fsA = f_src[rA];
    float vA = fsA + Mf; const float mcA = fmaxf(vA, 0.2f * vA) * LOG2E;

    {   // stage fd chunk (2048 floats)
        float4* d = (float4*)fd_s;
        const float4* src = (const float4*)(f_dst + jb0);
        d[t] = src[t]; d[256 + t] = src[256 + t];
    }
    {   // stage B tile 0 (contiguous 16 KB)
        const uint4* src = (const uint4*)(WhTb + (size_t)jw0 * 8192);
        uint4* dst = (uint4*)&Bt[0][0];
        dst[t] = src[t]; dst[256 + t] = src[256 + t];
        dst[512 + t] = src[512 + t]; dst[768 + t] = src[768 + t];
    }
    const unsigned int* bpA = BITS + (size_t)rA * 256 + jw0;
    unsigned int pwA = bpA[0];

    f32x4 acc[16];
#pragma unroll
    for (int ci = 0; ci < 16; ++ci) acc[ci] = (f32x4)0.f;
    float lsA = 0.f;
    __syncthreads();

    for (int js = 0; js < 64; ++js) {
        const int buf = js & 1;
        const int jn = (js + 1) & 63;
        // issue next-tile loads (consumed after MFMA section)
        const uint4* nsrc = (const uint4*)(WhTb + (size_t)(jw0 + jn) * 8192);
        uint4 g0 = nsrc[t], g1 = nsrc[256 + t], g2 = nsrc[512 + t], g3 = nsrc[768 + t];
        unsigned int nwA = bpA[jn];

        // fd fragment (quad-uniform LDS broadcast)
        const float* fdp = fd_s + js * 32 + q * 8;
        float4 f0 = *(const float4*)fdp, f1 = *(const float4*)(fdp + 4);
        float fdv[8] = { f0.x, f0.y, f0.z, f0.w, f1.x, f1.y, f1.z, f1.w };

        // P fragment in A-operand layout: A[m=l15][k=q*8+j]
        unsigned int bA = pwA >> (q * 8);
        short8 fragA;
#pragma unroll
        for (int k = 0; k < 8; ++k) {
            float tA = fsA + fdv[k];
            float eA = fmaxf(tA, 0.2f * tA);
            float pA = __builtin_amdgcn_exp2f(__builtin_fmaf(eA, LOG2E, -mcA));
            pA = ((bA >> k) & 1u) ? pA : 0.f;
            lsA += pA; fragA[k] = (short)f2bf(pA);
        }

        // MFMA over all 16 col-tiles (conflict-free ds_read_b128)
        const char* base = (const char*)&Bt[buf][0] + q * 4096 + l15 * 16;
#pragma unroll
        for (int ci = 0; ci < 16; ++ci) {
            short8 bf = *(const short8*)(base + ci * 256);
            acc[ci] = __builtin_amdgcn_mfma_f32_16x16x32_bf16(fragA, bf, acc[ci], 0, 0, 0);
        }

        // write next tile into other buffer
        { uint4* dst = (uint4*)&Bt[buf ^ 1][0];
          dst[t] = g0; dst[256 + t] = g1; dst[512 + t] = g2; dst[768 + t] = g3; }
        pwA = nwA;
        __syncthreads();
    }

    // row-sums: quads hold disjoint j
    lsA += __shfl_xor(lsA, 16, 64); lsA += __shfl_xor(lsA, 32, 64);
    if (lane < 16) Lp[(size_t)jc * 8192 + i0 + w * 16 + lane] = lsA;

    // f16 split-j partials
    _Float16* ap = ACCh + (size_t)jc * 2097152;
#pragma unroll
    for (int ci = 0; ci < 16; ++ci) {
#pragma unroll
        for (int reg = 0; reg < 4; ++reg) {
            int row = i0 + w * 16 + q * 4 + reg;
            ap[(size_t)row * 256 + ci * 16 + l15] = (_Float16)acc[ci][reg];
        }
    }
}

// ---------------- K4: combine partials, normalize, elu, f32 out ----------------
__global__ void k4_final(const _Float16* __restrict__ ACCh,
                         const float* __restrict__ Lp,
                         float* __restrict__ out) {
    int gid = blockIdx.x * 256 + threadIdx.x;   // 524288 threads x 4 elems
    int i = gid >> 6;
    float s0 = 0.f, s1 = 0.f, s2 = 0.f, s3 = 0.f;
#pragma unroll
    for (int jc = 0; jc < 4; ++jc) {
        h16x4 v = *(const h16x4*)(ACCh + (size_t)jc * 2097152 + (size_t)gid * 4);
        s0 += (float)v[0]; s1 += (float)v[1]; s2 += (float)v[2]; s3 += (float)v[3];
    }
    float L = 0.f;
#pragma unroll
    for (int jc = 0; jc < 4; ++jc) L += Lp[jc * 8192 + i];
    float inv = (L > 0.f) ? (1.0f / L) : 0.f;
    float h0 = s0 * inv, h1 = s1 * inv, h2 = s2 * inv, h3 = s3 * inv;
    float4 o;
    o.x = (h0 > 0.f) ? h0 : expm1f(h0);
    o.y = (h1 > 0.f) ? h1 : expm1f(h1);
    o.z = (h2 > 0.f) ? h2 : expm1f(h2);
    o.w = (h3 > 0.f) ? h3 : expm1f(h3);
    *(float4*)(out + (size_t)gid * 4) = o;
}

extern "C" void kernel_launch(void* const* d_in, const int* in_sizes, int n_in,
                              void* d_out, int out_size, void* d_ws, size_t ws_size,
                              hipStream_t stream) {
    (void)in_sizes; (void)n_in; (void)out_size; (void)ws_size;
    const float* X   = (const float*)d_in[0];
    const int*   adj = (const int*)d_in[1];
    const float* W   = (const float*)d_in[2];
    const float* a_s = (const float*)d_in[3];
    const float* a_d = (const float*)d_in[4];

    char* ws = (char*)d_ws;
    unsigned short* WTt  = (unsigned short*)(ws + OFF_WTT);
    unsigned short* WhTb = (unsigned short*)(ws + OFF_WHTB);
    unsigned long long* B64 = (unsigned long long*)(ws + OFF_BITS);
    unsigned int*   BITS = (unsigned int*)(ws + OFF_BITS);
    float*          fsrc = (float*)(ws + OFF_FSRC);
    float*          fdst = (float*)(ws + OFF_FDST);
    unsigned int*   Mkey = (unsigned int*)(ws + OFF_MKEY);
    float*          Lp   = (float*)(ws + OFF_LP);
    _Float16*       ACCh = (_Float16*)(ws + OFF_ACCH);
    float*          out  = (float*)d_out;

    k0_init<<<dim3(256), dim3(256), 0, stream>>>(W, WTt, Mkey);
    k_pack<<<dim3(1024), dim3(256), 0, stream>>>(adj, B64);
    k1_stage1<<<dim3(256), dim3(256), 0, stream>>>(X, WTt, a_s, a_d, WhTb, fsrc, fdst, Mkey);
    k2_flash<<<dim3(128, 4), dim3(256), 0, stream>>>(BITS, WhTb, fsrc, fdst, Mkey, Lp, ACCh);
    k4_final<<<dim3(2048), dim3(256), 0, stream>>>(ACCh, Lp, out);
}